// Round 9
// baseline (26.945 us; speedup 1.0000x reference)
//
#include <hip/hip_runtime.h>

// MTGP covariance, round 9: fragment-packed global operands, barrier-free waves.
// cov[i,j] = sum_z W[ti,z]W[tj,z]*th[z,0]*exp(-0.5*th[z,1]*||Xi-Xj||^2) + 0.002*I
// M=4096, D=64, Z=4, fp32 in/out.
// pack: X -> Ph/Pl (bf16 hi/lo, MFMA-fragment-ordered) + row norms, in d_ws.
//   frag layout: 16-row slab s16, k-half k0 -> frag id f=(s16*2+k0); lane
//   l=(kg,r16) holds 16B = x[row=slab+r16][32k0+4kg+0..3, 32k0+16+4kg+0..3]
//   at Ph[f*512 + l*8] (ush). A wave's frag load = contiguous coalesced 1KB.
// main: 8256 upper-tri 32x32 wave-tiles (2 waves/block, no LDS, no barriers):
//   16 coalesced dwordx4 frag loads + 24 mfma 16x16x32 bf16 (hh+hl+lh) ->
//   fused RBF epilogue -> direct + (off-diag) transpose stores, exact-once.
// Same k-permutation on A and B => dots unchanged (verified R7, absmax .0156).

#define M_PTS 4096
#define DIM 64
#define JITTER_F 0.002f
#define NEG_HALF_LOG2E (-0.72134752044448170f)  // -0.5*log2(e)
#define NITEM 8256                               // 128*129/2
#define NBLK (NITEM / 2)                         // 4128

typedef __attribute__((ext_vector_type(8))) short short8v;   // 8 bf16
typedef __attribute__((ext_vector_type(4))) float f32x4;

union FragU { short8v v; uint4 u; };

__device__ __forceinline__ float fast_exp2(float x) {
#if defined(__has_builtin)
#if __has_builtin(__builtin_amdgcn_exp2f)
  return __builtin_amdgcn_exp2f(x);
#else
  return exp2f(x);
#endif
#else
  return exp2f(x);
#endif
}

__device__ __forceinline__ unsigned bfr(float x) {  // fp32 -> bf16 (rne), as u16
  unsigned u = __float_as_uint(x);
  return (u + 0x7FFFu + ((u >> 16) & 1u)) >> 16;
}
__device__ __forceinline__ float bff(unsigned h) {  // bf16 bits -> fp32
  return __uint_as_float(h << 16);
}

// ---------------- pack: hi/lo split into fragment order + row norms ----------------
__global__ __launch_bounds__(256) void mtgp_pack(
    const float* __restrict__ X, unsigned short* __restrict__ Ph,
    unsigned short* __restrict__ Pl, float* __restrict__ sqn) {
  const int t = blockIdx.x * 256 + threadIdx.x;  // 0..8191
  const int row = t >> 1, k0 = t & 1;            // thread owns 32 elems of one row
  const float4* xr = (const float4*)(X + (size_t)row * DIM + k0 * 32);
  float va[32];
  float s = 0.0f;
#pragma unroll
  for (int i = 0; i < 8; ++i) {
    const float4 vv = xr[i];
    va[4 * i + 0] = vv.x; va[4 * i + 1] = vv.y;
    va[4 * i + 2] = vv.z; va[4 * i + 3] = vv.w;
    s = fmaf(vv.x, vv.x, s); s = fmaf(vv.y, vv.y, s);
    s = fmaf(vv.z, vv.z, s); s = fmaf(vv.w, vv.w, s);
  }
  s += __shfl_xor(s, 1);                         // (row,k0=0)+(row,k0=1) pair
  if (k0 == 0) sqn[row] = s;
  const int fbase = ((row >> 4) * 2 + k0) * 512; // frag id * 512 ush
#pragma unroll
  for (int kg = 0; kg < 4; ++kg) {
    unsigned h[8], l[8];
#pragma unroll
    for (int j = 0; j < 4; ++j) {
      const float x0 = va[4 * kg + j], x1 = va[16 + 4 * kg + j];
      h[j] = bfr(x0);     l[j] = bfr(x0 - bff(h[j]));
      h[4 + j] = bfr(x1); l[4 + j] = bfr(x1 - bff(h[4 + j]));
    }
    const uint4 hv = make_uint4(h[0] | (h[1] << 16), h[2] | (h[3] << 16),
                                h[4] | (h[5] << 16), h[6] | (h[7] << 16));
    const uint4 lv = make_uint4(l[0] | (l[1] << 16), l[2] | (l[3] << 16),
                                l[4] | (l[5] << 16), l[6] | (l[7] << 16));
    const int lofs = fbase + (((kg << 4) + (row & 15)) << 3);  // lane*8 ush
    *(uint4*)&Ph[lofs] = hv;
    *(uint4*)&Pl[lofs] = lv;
  }
}

// ---------------- main: one wave = one 32x32 upper-tri tile ----------------
__global__ __launch_bounds__(128, 6) void mtgp_main(
    const unsigned short* __restrict__ Ph, const unsigned short* __restrict__ Pl,
    const float* __restrict__ sqn, const float* __restrict__ W,
    const float* __restrict__ theta, float* __restrict__ out) {
  const int wid = threadIdx.x >> 6;
  const int lane = threadIdx.x & 63;
  const int item = blockIdx.x * 2 + wid;         // 0..8255

  // decode item -> (u, v), v >= u, 128 slabs; prefix(u) = u*(257-u)/2
  int u = (int)((257.0f - sqrtf((float)(66049 - 8 * item))) * 0.5f);
  if (u < 0) u = 0;
  if (u > 127) u = 127;
  while (u > 0 && u * (257 - u) / 2 > item) --u;
  while (u < 127 && (u + 1) * (256 - u) / 2 <= item) ++u;
  const int v = u + (item - u * (257 - u) / 2);
  const int gi0 = u << 5, gj0 = v << 5;

  const int r16 = lane & 15, kg = lane >> 4, kg4 = kg << 2;
  const int l8 = lane << 3;                      // lane ush offset within frag

  f32x4 acc[2][2];
#pragma unroll
  for (int p = 0; p < 2; ++p) { acc[p][0] = (f32x4)0.0f; acc[p][1] = (f32x4)0.0f; }

#pragma unroll 1
  for (int k0 = 0; k0 < 2; ++k0) {
    FragU ah[2], al[2], bh[2], bl[2];
#pragma unroll
    for (int p = 0; p < 2; ++p) {
      const int fa = ((2 * u + p) * 2 + k0) * 512 + l8;
      const int fb = ((2 * v + p) * 2 + k0) * 512 + l8;
      ah[p].u = *(const uint4*)&Ph[fa];
      al[p].u = *(const uint4*)&Pl[fa];
      bh[p].u = *(const uint4*)&Ph[fb];
      bl[p].u = *(const uint4*)&Pl[fb];
    }
#pragma unroll
    for (int p = 0; p < 2; ++p)
#pragma unroll
      for (int q = 0; q < 2; ++q) {
        acc[p][q] = __builtin_amdgcn_mfma_f32_16x16x32_bf16(ah[p].v, bh[q].v, acc[p][q], 0, 0, 0);
        acc[p][q] = __builtin_amdgcn_mfma_f32_16x16x32_bf16(ah[p].v, bl[q].v, acc[p][q], 0, 0, 0);
        acc[p][q] = __builtin_amdgcn_mfma_f32_16x16x32_bf16(al[p].v, bh[q].v, acc[p][q], 0, 0, 0);
      }
  }

  // ---- epilogue ----
  const int ti = u >> 5, tj = v >> 5;            // 32 slabs of 32 rows per task
  float czv[4], ezv[4];
#pragma unroll
  for (int z = 0; z < 4; ++z) {
    czv[z] = W[ti * 4 + z] * W[tj * 4 + z] * theta[2 * z];
    ezv[z] = NEG_HALF_LOG2E * theta[2 * z + 1];
  }
  f32x4 sqr[2];
#pragma unroll
  for (int p = 0; p < 2; ++p) sqr[p] = *(const f32x4*)&sqn[gi0 + p * 16 + kg4];
  float sqc[2];
#pragma unroll
  for (int q = 0; q < 2; ++q) sqc[q] = sqn[gj0 + q * 16 + r16];

#pragma unroll
  for (int p = 0; p < 2; ++p)
#pragma unroll
    for (int q = 0; q < 2; ++q)
#pragma unroll
      for (int rr = 0; rr < 4; ++rr) {
        const float d = acc[p][q][rr];
        const float sd = fmaxf(fmaf(-2.0f, d, sqr[p][rr] + sqc[q]), 0.0f);
        float val = czv[0] * fast_exp2(ezv[0] * sd);
        val = fmaf(czv[1], fast_exp2(ezv[1] * sd), val);
        val = fmaf(czv[2], fast_exp2(ezv[2] * sd), val);
        val = fmaf(czv[3], fast_exp2(ezv[3] * sd), val);
        if (u == v && p * 16 + kg4 + rr == q * 16 + r16) val += JITTER_F;
        acc[p][q][rr] = val;
      }

  // ---- direct store: rows gi0.., cols gj0.. (full tile) ----
#pragma unroll
  for (int p = 0; p < 2; ++p)
#pragma unroll
    for (int rr = 0; rr < 4; ++rr) {
      float* rp = out + (size_t)(gi0 + p * 16 + kg4 + rr) * M_PTS + gj0 + r16;
      rp[0] = acc[p][0][rr];
      rp[16] = acc[p][1][rr];
    }
  // ---- transpose store (off-diagonal only): mirror to strictly-below region ----
  if (u != v) {
#pragma unroll
    for (int q = 0; q < 2; ++q)
#pragma unroll
      for (int p = 0; p < 2; ++p) {
        f32x4* tp = (f32x4*)(out + (size_t)(gj0 + q * 16 + r16) * M_PTS + gi0 + p * 16 + kg4);
        *tp = acc[p][q];
      }
  }
}

extern "C" void kernel_launch(void* const* d_in, const int* in_sizes, int n_in,
                              void* d_out, int out_size, void* d_ws, size_t ws_size,
                              hipStream_t stream) {
  const float* x     = (const float*)d_in[0];   // (4,1024,64)
  const float* W     = (const float*)d_in[1];   // (4,4)
  const float* theta = (const float*)d_in[2];   // (4,2)
  float* out = (float*)d_out;                   // (4096,4096)

  // workspace: sqn (16 KB) | Ph (512 KB) | Pl (512 KB)
  float* sqn = (float*)d_ws;
  unsigned short* Ph = (unsigned short*)((char*)d_ws + 16384);
  unsigned short* Pl = (unsigned short*)((char*)d_ws + 16384 + 524288);

  mtgp_pack<<<dim3(32), dim3(256), 0, stream>>>(x, Ph, Pl, sqn);
  mtgp_main<<<dim3(NBLK), dim3(128), 0, stream>>>(Ph, Pl, sqn, W, theta, out);
}